// Round 6
// baseline (2913.087 us; speedup 1.0000x reference)
//
#include <hip/hip_runtime.h>

#define Bb 1024
#define Ss 512
#define Ee 128
#define Hh 256
#define Vv 128
#define Cc 18
#define PSTEPS 1024

// Static LDS map (40960 B):
#define H1OFF 8192    // h double buffer: [0,8192) + [8192,16384), 16 rows x 512B, XOR-swizzled
#define YOFF  16384   // y bf16 capture: 8192 B (same layout/swizzle as one h buffer)
#define ZOFF  24576   // z f32 [16][256] for the FC head

typedef __attribute__((ext_vector_type(8))) short short8;
typedef __attribute__((ext_vector_type(4))) float f32x4;
typedef __attribute__((ext_vector_type(2))) int int2v;

__device__ __forceinline__ unsigned short f2bf(float f) {
  union { float f; unsigned u; } v; v.f = f;
  return (unsigned short)((v.u + 0x7FFFu + ((v.u >> 16) & 1u)) >> 16);
}

__device__ __forceinline__ f32x4 mfma16(short8 a, short8 b, f32x4 c) {
  return __builtin_amdgcn_mfma_f32_16x16x32_bf16(a, b, c, 0, 0, 0);
}

// tanh = 1 - 2/(e^{2x}+1); correct limits at +-inf, no clamp needed.
__device__ __forceinline__ float ftanh(float x) {
  float e2 = __expf(2.0f * x);
  return 1.0f - 2.0f * __builtin_amdgcn_rcpf(e2 + 1.0f);
}

__device__ __forceinline__ unsigned cvtpk(float a, float b) {
  unsigned r;
  asm("v_cvt_pk_bf16_f32 %0, %1, %2" : "=v"(r) : "v"(a), "v"(b));
  return r;  // lo16 = bf16(a), hi16 = bf16(b)
}

// Load a 64-col slice of a [256][256] f32 row-major matrix as bf16 A-fragments.
__device__ __forceinline__ void load_wfrags(const float* __restrict__ W, int j0, int l15, int g,
                                            short8 wfrag[4][8]) {
#pragma unroll
  for (int mt = 0; mt < 4; ++mt) {
    const float* wrow = W + (j0 + mt * 16 + l15) * Hh;
#pragma unroll
    for (int kt = 0; kt < 8; ++kt) {
      const float* wp = wrow + kt * 32 + g * 8;
      f32x4 a = *(const f32x4*)(wp);
      f32x4 b = *(const f32x4*)(wp + 4);
      short8 f;
      f[0] = (short)f2bf(a.x); f[1] = (short)f2bf(a.y);
      f[2] = (short)f2bf(a.z); f[3] = (short)f2bf(a.w);
      f[4] = (short)f2bf(b.x); f[5] = (short)f2bf(b.y);
      f[6] = (short)f2bf(b.z); f[7] = (short)f2bf(b.w);
      wfrag[mt][kt] = f;
    }
  }
}

// ---------------- Kernel 1: T[v][j] = emb[v].W_ih[j] + b_ih[j] + b_hh[j] (f32) ----------------
__global__ void prep_T(const float* __restrict__ emb, const float* __restrict__ W_ih,
                       const float* __restrict__ b_ih, const float* __restrict__ b_hh,
                       float* __restrict__ T) {
  __shared__ float elds[Ee];
  const int v = blockIdx.x, j = threadIdx.x;
  if (j < Ee) elds[j] = emb[v * Ee + j];
  __syncthreads();
  float s = b_ih[j] + b_hh[j];
  const float* wr = W_ih + j * Ee;
#pragma unroll 8
  for (int e = 0; e < Ee; e += 4) {
    f32x4 w = *(const f32x4*)(wr + e);
    f32x4 x = *(const f32x4*)(elds + e);
    s += w.x * x.x + w.y * x.y + w.z * x.z + w.w * x.w;
  }
  T[v * Hh + j] = s;
}

// ================= ABLATION PROBES =================
// MODE bits: 1 = tanh, 2 = T global prefetch, 4 = barrier. Full structure = 7.
// Probes run PSTEPS fixed steps (2x real) so per-step cost = dur_us*2400/PSTEPS cyc.
template <int MODE, int PAR>
__device__ __forceinline__ void probe_phase(char* smem, const short8 (&wf)[4][8],
                                            const int (&roff)[8], const int (&woff)[4],
                                            const float* __restrict__ T,
                                            const int* __restrict__ xrow,
                                            int t, int j0, int g,
                                            f32x4 (&tcur)[4], int& xv_use, int& xv_inf) {
  char* RB = smem + (PAR ? H1OFF : 0);
  char* WB = smem + (PAR ? 0 : H1OFF);

  f32x4 tn0, tn1, tn2, tn3;
  int xv_new = 0;
  if constexpr (MODE & 2) {
    const float* tp = T + xv_use * Hh + j0 + g * 4;
    tn0 = *(const f32x4*)(tp);
    tn1 = *(const f32x4*)(tp + 16);
    tn2 = *(const f32x4*)(tp + 32);
    tn3 = *(const f32x4*)(tp + 48);
    xv_new = xrow[(t + 3) & (Ss - 1)];
  }

  short8 hf[8];
  hf[0] = *(const short8*)(RB + roff[0]);
  hf[1] = *(const short8*)(RB + roff[1]);

  f32x4 aA[4], aB[4];
  const f32x4 Z4 = {0.f, 0.f, 0.f, 0.f};
#pragma unroll
  for (int mt = 0; mt < 4; ++mt) {
    aA[mt] = (MODE & 2) ? tcur[mt] : Z4;
    aB[mt] = Z4;
  }

#pragma unroll
  for (int kt = 0; kt < 8; ++kt) {
    if (kt < 6) hf[kt + 2] = *(const short8*)(RB + roff[kt + 2]);
    if ((kt & 1) == 0) {
#pragma unroll
      for (int mt = 0; mt < 4; ++mt) aA[mt] = mfma16(wf[mt][kt], hf[kt], aA[mt]);
    } else {
#pragma unroll
      for (int mt = 0; mt < 4; ++mt) aB[mt] = mfma16(wf[mt][kt], hf[kt], aB[mt]);
    }
  }

#pragma unroll
  for (int mt = 0; mt < 4; ++mt) {
    float s0 = aA[mt].x + aB[mt].x;
    float s1 = aA[mt].y + aB[mt].y;
    float s2 = aA[mt].z + aB[mt].z;
    float s3 = aA[mt].w + aB[mt].w;
    float v0, v1, v2, v3;
    if constexpr (MODE & 1) {
      v0 = ftanh(s0); v1 = ftanh(s1); v2 = ftanh(s2); v3 = ftanh(s3);
    } else {
      v0 = s0; v1 = s1; v2 = s2; v3 = s3;
    }
    int2v pk;
    pk.x = (int)cvtpk(v0, v1);
    pk.y = (int)cvtpk(v2, v3);
    *(int2v*)(WB + woff[mt]) = pk;
  }

  if constexpr (MODE & 2) {
    tcur[0] = tn0; tcur[1] = tn1; tcur[2] = tn2; tcur[3] = tn3;
    xv_use = xv_inf;
    xv_inf = xv_new;
  }

  if constexpr (MODE & 4) {
    asm volatile("s_waitcnt lgkmcnt(0)" ::: "memory");
    __builtin_amdgcn_sched_barrier(0);
    __builtin_amdgcn_s_barrier();
    __builtin_amdgcn_sched_barrier(0);
  }
}

template <int MODE>
__global__ __launch_bounds__(256, 1)
void rnn_probe(const int* __restrict__ x_in, const float* __restrict__ W_hh,
               const float* __restrict__ T, float* __restrict__ po) {
  __shared__ __align__(16) char smem[40960];
  const int tid  = threadIdx.x;
  const int lane = tid & 63;
  const int wave = tid >> 6;
  const int l15  = lane & 15;
  const int g    = lane >> 4;
  const int j0   = wave * 64;
  const int grow = blockIdx.x * 16;
  const int r    = l15;
  const int swz  = (r & 7) << 4;
  const int rowb = r * 512;

  short8 wfrag[4][8];
  load_wfrags(W_hh, j0, l15, g, wfrag);

  {
    int2v* hz = (int2v*)smem;
    const int2v z2 = {0, 0};
    for (int i = tid; i < 1024; i += 256) hz[i] = z2;
  }

  int roff[8], woff[4];
#pragma unroll
  for (int kt = 0; kt < 8; ++kt) roff[kt] = rowb + ((kt * 64 + g * 16) ^ swz);
#pragma unroll
  for (int mt = 0; mt < 4; ++mt) woff[mt] = rowb + (((j0 + mt * 16 + g * 4) * 2) ^ swz);

  const int* xrow = x_in + (grow + r) * Ss;
  f32x4 tcur[4];
  int xv_use = 0, xv_inf = 0;
  if constexpr (MODE & 2) {
    const int xv0 = xrow[0];
    const float* tp = T + xv0 * Hh + j0 + g * 4;
    tcur[0] = *(const f32x4*)(tp);
    tcur[1] = *(const f32x4*)(tp + 16);
    tcur[2] = *(const f32x4*)(tp + 32);
    tcur[3] = *(const f32x4*)(tp + 48);
    xv_use = xrow[1];
    xv_inf = xrow[2];
  }
  __syncthreads();

  for (int t = 0; t < PSTEPS; t += 2) {
    probe_phase<MODE, 0>(smem, wfrag, roff, woff, T, xrow, t,     j0, g, tcur, xv_use, xv_inf);
    probe_phase<MODE, 1>(smem, wfrag, roff, woff, T, xrow, t + 1, j0, g, tcur, xv_use, xv_inf);
  }

  __syncthreads();
  // keep-alive: loop state -> global (prevents whole-loop DCE, rule #17)
  po[blockIdx.x * 256 + tid] = (float)((short*)smem)[tid] + ((MODE & 2) ? (float)xv_use : 0.f);
}

// ---------------- real RNN step (unchanged from R5, validated) ----------------
template <int PAR>
__device__ __forceinline__ void step_phase(char* smem, const short8 (&wf)[4][8],
                                           const int (&roff)[8], const int (&woff)[4],
                                           const float* __restrict__ T,
                                           const int* __restrict__ xrow,
                                           int t, int mylen, int j0, int g,
                                           f32x4 (&tcur)[4], int& xv_use, int& xv_inf) {
  char* RB = smem + (PAR ? H1OFF : 0);
  char* WB = smem + (PAR ? 0 : H1OFF);

  const float* tp = T + xv_use * Hh + j0 + g * 4;
  f32x4 tn0 = *(const f32x4*)(tp);
  f32x4 tn1 = *(const f32x4*)(tp + 16);
  f32x4 tn2 = *(const f32x4*)(tp + 32);
  f32x4 tn3 = *(const f32x4*)(tp + 48);
  const int xv_new = xrow[min(t + 3, Ss - 1)];

  short8 hf[8];
  hf[0] = *(const short8*)(RB + roff[0]);
  hf[1] = *(const short8*)(RB + roff[1]);

  f32x4 aA[4], aB[4];
  const f32x4 Z4 = {0.f, 0.f, 0.f, 0.f};
#pragma unroll
  for (int mt = 0; mt < 4; ++mt) { aA[mt] = tcur[mt]; aB[mt] = Z4; }

#pragma unroll
  for (int kt = 0; kt < 8; ++kt) {
    if (kt < 6) hf[kt + 2] = *(const short8*)(RB + roff[kt + 2]);
    if ((kt & 1) == 0) {
#pragma unroll
      for (int mt = 0; mt < 4; ++mt) aA[mt] = mfma16(wf[mt][kt], hf[kt], aA[mt]);
    } else {
#pragma unroll
      for (int mt = 0; mt < 4; ++mt) aB[mt] = mfma16(wf[mt][kt], hf[kt], aB[mt]);
    }
  }

  const bool emit = (t == mylen - 1);
#pragma unroll
  for (int mt = 0; mt < 4; ++mt) {
    float s0 = aA[mt].x + aB[mt].x;
    float s1 = aA[mt].y + aB[mt].y;
    float s2 = aA[mt].z + aB[mt].z;
    float s3 = aA[mt].w + aB[mt].w;
    int2v pk;
    pk.x = (int)cvtpk(ftanh(s0), ftanh(s1));
    pk.y = (int)cvtpk(ftanh(s2), ftanh(s3));
    *(int2v*)(WB + woff[mt]) = pk;
    if (emit) *(int2v*)(smem + YOFF + woff[mt]) = pk;
  }

  tcur[0] = tn0; tcur[1] = tn1; tcur[2] = tn2; tcur[3] = tn3;
  xv_use = xv_inf;
  xv_inf = xv_new;

  asm volatile("s_waitcnt lgkmcnt(0)" ::: "memory");
  __builtin_amdgcn_sched_barrier(0);
  __builtin_amdgcn_s_barrier();
  __builtin_amdgcn_sched_barrier(0);
}

__global__ __launch_bounds__(256, 1)
void rnn_fused(const int* __restrict__ x_in, const int* __restrict__ x_len,
               const float* __restrict__ W_hh, const float* __restrict__ T,
               const float* __restrict__ fc1_w, const float* __restrict__ fc1_b,
               const float* __restrict__ fc2_w, const float* __restrict__ fc2_b,
               float* __restrict__ out) {
  __shared__ __align__(16) char smem[40960];

  const int tid  = threadIdx.x;
  const int lane = tid & 63;
  const int wave = tid >> 6;
  const int l15  = lane & 15;
  const int g    = lane >> 4;
  const int j0   = wave * 64;
  const int grow = blockIdx.x * 16;
  const int r    = l15;
  const int swz  = (r & 7) << 4;
  const int rowb = r * 512;

  short8 wfrag[4][8];
  load_wfrags(W_hh, j0, l15, g, wfrag);

  const int mylen = x_len[grow + r];
  int maxlen = 1;
#pragma unroll
  for (int i = 0; i < 16; ++i) maxlen = max(maxlen, x_len[grow + i]);

  {
    int2v* hz = (int2v*)smem;
    const int2v z2 = {0, 0};
    for (int i = tid; i < 1024; i += 256) hz[i] = z2;
  }

  int roff[8], woff[4];
#pragma unroll
  for (int kt = 0; kt < 8; ++kt) roff[kt] = rowb + ((kt * 64 + g * 16) ^ swz);
#pragma unroll
  for (int mt = 0; mt < 4; ++mt) woff[mt] = rowb + (((j0 + mt * 16 + g * 4) * 2) ^ swz);

  const int* xrow = x_in + (grow + r) * Ss;
  f32x4 tcur[4];
  {
    const int xv0 = xrow[0];
    const float* tp = T + xv0 * Hh + j0 + g * 4;
    tcur[0] = *(const f32x4*)(tp);
    tcur[1] = *(const f32x4*)(tp + 16);
    tcur[2] = *(const f32x4*)(tp + 32);
    tcur[3] = *(const f32x4*)(tp + 48);
  }
  int xv_use = xrow[min(1, Ss - 1)];
  int xv_inf = xrow[min(2, Ss - 1)];

  __syncthreads();

  const int mx2 = (maxlen + 1) & ~1;
  for (int t = 0; t < mx2; t += 2) {
    step_phase<0>(smem, wfrag, roff, woff, T, xrow, t,     mylen, j0, g, tcur, xv_use, xv_inf);
    step_phase<1>(smem, wfrag, roff, woff, T, xrow, t + 1, mylen, j0, g, tcur, xv_use, xv_inf);
  }

  // fused FC head
  short8 ffrag[4][8];
  load_wfrags(fc1_w, j0, l15, g, ffrag);
  f32x4 fb[4];
#pragma unroll
  for (int mt = 0; mt < 4; ++mt)
    fb[mt] = *(const f32x4*)(fc1_b + j0 + mt * 16 + g * 4);

  short8 yf[8];
#pragma unroll
  for (int kt = 0; kt < 8; ++kt) yf[kt] = *(const short8*)(smem + YOFF + roff[kt]);

  const f32x4 Z4 = {0.f, 0.f, 0.f, 0.f};
  f32x4 acc[4], acc2[4];
#pragma unroll
  for (int mt = 0; mt < 4; ++mt) { acc[mt] = fb[mt]; acc2[mt] = Z4; }
#pragma unroll
  for (int kt = 0; kt < 4; ++kt)
#pragma unroll
    for (int mt = 0; mt < 4; ++mt)
      acc[mt] = mfma16(ffrag[mt][kt], yf[kt], acc[mt]);
#pragma unroll
  for (int kt = 4; kt < 8; ++kt)
#pragma unroll
    for (int mt = 0; mt < 4; ++mt)
      acc2[mt] = mfma16(ffrag[mt][kt], yf[kt], acc2[mt]);

  float* z_ld = (float*)(smem + ZOFF);
#pragma unroll
  for (int mt = 0; mt < 4; ++mt) {
    f32x4 z;
    z.x = fmaxf(acc[mt].x + acc2[mt].x, 0.f);
    z.y = fmaxf(acc[mt].y + acc2[mt].y, 0.f);
    z.z = fmaxf(acc[mt].z + acc2[mt].z, 0.f);
    z.w = fmaxf(acc[mt].w + acc2[mt].w, 0.f);
    *(f32x4*)(z_ld + r * 256 + j0 + mt * 16 + g * 4) = z;
  }
  __syncthreads();

  for (int idx = tid; idx < 16 * Cc; idx += 256) {
    const int rr = idx / Cc, c = idx % Cc;
    float s = fc2_b[c];
    const float* wr2 = fc2_w + c * Hh;
    const float* zr  = z_ld + rr * 256;
#pragma unroll 4
    for (int k = 0; k < Hh; k += 4) {
      f32x4 w = *(const f32x4*)(wr2 + k);
      f32x4 z = *(const f32x4*)(zr + k);
      s += w.x * z.x + w.y * z.y + w.z * z.z + w.w * z.w;
    }
    out[(grow + rr) * Cc + c] = s;
  }
}

extern "C" void kernel_launch(void* const* d_in, const int* in_sizes, int n_in,
                              void* d_out, int out_size, void* d_ws, size_t ws_size,
                              hipStream_t stream) {
  const int*   x_in  = (const int*)d_in[0];
  const int*   x_len = (const int*)d_in[1];
  const float* emb   = (const float*)d_in[2];
  const float* W_ih  = (const float*)d_in[3];
  const float* W_hh  = (const float*)d_in[4];
  const float* b_ih  = (const float*)d_in[5];
  const float* b_hh  = (const float*)d_in[6];
  const float* fc1_w = (const float*)d_in[7];
  const float* fc1_b = (const float*)d_in[8];
  const float* fc2_w = (const float*)d_in[9];
  const float* fc2_b = (const float*)d_in[10];
  float* out = (float*)d_out;

  float* T  = (float*)d_ws;        // 128*256 f32 = 128 KB
  float* po = T + Vv * Hh;         // probe sinks: 4 x 64 KB

  prep_T<<<Vv, Hh, 0, stream>>>(emb, W_ih, b_ih, b_hh, T);

  // ---- ablation probes (1024 fixed steps each; results discarded) ----
  rnn_probe<3><<<Bb / 16, 256, 0, stream>>>(x_in, W_hh, T, po);            // full - barrier
  rnn_probe<5><<<Bb / 16, 256, 0, stream>>>(x_in, W_hh, T, po + 16384);    // full - T prefetch
  rnn_probe<6><<<Bb / 16, 256, 0, stream>>>(x_in, W_hh, T, po + 32768);    // full - tanh
  rnn_probe<0><<<Bb / 16, 256, 0, stream>>>(x_in, W_hh, T, po + 49152);    // bare floor

  // ---- real kernel (unchanged from R5) ----
  rnn_fused<<<Bb / 16, 256, 0, stream>>>(x_in, x_len, W_hh, T,
                                         fc1_w, fc1_b, fc2_w, fc2_b, out);
}

// Round 7
// 432.949 us; speedup vs baseline: 6.7285x; 6.7285x over previous
//
#include <hip/hip_runtime.h>

#define Bb 1024
#define Ss 512
#define Ee 128
#define Hh 256
#define Vv 128
#define Cc 18

// Static LDS map (40960 B):
#define H1OFF 8192    // h double buffer: [0,8192) + [8192,16384), 16 rows x 512B, XOR-swizzled
#define YOFF  16384   // y bf16 capture: 8192 B (same layout/swizzle as one h buffer)
#define ZOFF  24576   // z f32 [16][256] for the FC head

typedef __attribute__((ext_vector_type(8))) short short8;
typedef __attribute__((ext_vector_type(4))) float f32x4;
typedef __attribute__((ext_vector_type(2))) int int2v;

__device__ __forceinline__ unsigned short f2bf(float f) {
  union { float f; unsigned u; } v; v.f = f;
  return (unsigned short)((v.u + 0x7FFFu + ((v.u >> 16) & 1u)) >> 16);
}

__device__ __forceinline__ f32x4 mfma16(short8 a, short8 b, f32x4 c) {
  return __builtin_amdgcn_mfma_f32_16x16x32_bf16(a, b, c, 0, 0, 0);
}

// tanh = 1 - 2/(e^{2x}+1); correct limits at +-inf, no clamp needed.
__device__ __forceinline__ float ftanh(float x) {
  float e2 = __expf(2.0f * x);
  return 1.0f - 2.0f * __builtin_amdgcn_rcpf(e2 + 1.0f);
}

__device__ __forceinline__ unsigned cvtpk(float a, float b) {
  unsigned r;
  asm("v_cvt_pk_bf16_f32 %0, %1, %2" : "=v"(r) : "v"(a), "v"(b));
  return r;  // lo16 = bf16(a), hi16 = bf16(b)
}

// Load a 32-col slice (2 mt tiles) of a [256][256] f32 row-major matrix as bf16 A-fragments.
__device__ __forceinline__ void load_wfrags2(const float* __restrict__ W, int j0, int l15, int g,
                                             short8 wfrag[2][8]) {
#pragma unroll
  for (int mt = 0; mt < 2; ++mt) {
    const float* wrow = W + (j0 + mt * 16 + l15) * Hh;
#pragma unroll
    for (int kt = 0; kt < 8; ++kt) {
      const float* wp = wrow + kt * 32 + g * 8;
      f32x4 a = *(const f32x4*)(wp);
      f32x4 b = *(const f32x4*)(wp + 4);
      short8 f;
      f[0] = (short)f2bf(a.x); f[1] = (short)f2bf(a.y);
      f[2] = (short)f2bf(a.z); f[3] = (short)f2bf(a.w);
      f[4] = (short)f2bf(b.x); f[5] = (short)f2bf(b.y);
      f[6] = (short)f2bf(b.z); f[7] = (short)f2bf(b.w);
      wfrag[mt][kt] = f;
    }
  }
}

// ---------------- Kernel 1: T[v][j] = emb[v].W_ih[j] + b_ih[j] + b_hh[j] (f32) ----------------
__global__ void prep_T(const float* __restrict__ emb, const float* __restrict__ W_ih,
                       const float* __restrict__ b_ih, const float* __restrict__ b_hh,
                       float* __restrict__ T) {
  __shared__ float elds[Ee];
  const int v = blockIdx.x, j = threadIdx.x;
  if (j < Ee) elds[j] = emb[v * Ee + j];
  __syncthreads();
  float s = b_ih[j] + b_hh[j];
  const float* wr = W_ih + j * Ee;
#pragma unroll 8
  for (int e = 0; e < Ee; e += 4) {
    f32x4 w = *(const f32x4*)(wr + e);
    f32x4 x = *(const f32x4*)(elds + e);
    s += w.x * x.x + w.y * x.y + w.z * x.z + w.w * x.w;
  }
  T[v * Hh + j] = s;
}

// ---------------- one RNN step (8-wave version: 32 j-cols per wave) ----------------
// Pipeline invariants: tcur = T rows for x[t]; xv_use = x[t+1]; xv_inf = x[t+2];
// the token load issued this step is x[t+3].
template <int PAR>
__device__ __forceinline__ void step_phase(char* smem, const short8 (&wf)[2][8],
                                           const int (&roff)[8], const int (&woff)[2],
                                           const float* __restrict__ T,
                                           const int* __restrict__ xrow,
                                           int t, int mylen, int j0, int g,
                                           f32x4 (&tcur)[2], int& xv_use, int& xv_inf) {
  char* RB = smem + (PAR ? H1OFF : 0);
  char* WB = smem + (PAR ? 0 : H1OFF);

  // (1) next step's T gather (f32 -> registers) + token for t+3
  const float* tp = T + xv_use * Hh + j0 + g * 4;
  f32x4 tn0 = *(const f32x4*)(tp);
  f32x4 tn1 = *(const f32x4*)(tp + 16);
  const int xv_new = xrow[min(t + 3, Ss - 1)];

  // (2) h-reads pipelined into the MFMA stream
  short8 hf[8];
  hf[0] = *(const short8*)(RB + roff[0]);
  hf[1] = *(const short8*)(RB + roff[1]);

  f32x4 aA[2], aB[2];
  const f32x4 Z4 = {0.f, 0.f, 0.f, 0.f};
#pragma unroll
  for (int mt = 0; mt < 2; ++mt) { aA[mt] = tcur[mt]; aB[mt] = Z4; }

#pragma unroll
  for (int kt = 0; kt < 8; ++kt) {
    if (kt < 6) hf[kt + 2] = *(const short8*)(RB + roff[kt + 2]);
    if ((kt & 1) == 0) {
#pragma unroll
      for (int mt = 0; mt < 2; ++mt) aA[mt] = mfma16(wf[mt][kt], hf[kt], aA[mt]);
    } else {
#pragma unroll
      for (int mt = 0; mt < 2; ++mt) aB[mt] = mfma16(wf[mt][kt], hf[kt], aB[mt]);
    }
  }

  // (3) epilogue: combine, tanh, pack, write
  const bool emit = (t == mylen - 1);
#pragma unroll
  for (int mt = 0; mt < 2; ++mt) {
    float s0 = aA[mt].x + aB[mt].x;
    float s1 = aA[mt].y + aB[mt].y;
    float s2 = aA[mt].z + aB[mt].z;
    float s3 = aA[mt].w + aB[mt].w;
    int2v pk;
    pk.x = (int)cvtpk(ftanh(s0), ftanh(s1));
    pk.y = (int)cvtpk(ftanh(s2), ftanh(s3));
    *(int2v*)(WB + woff[mt]) = pk;
    if (emit) *(int2v*)(smem + YOFF + woff[mt]) = pk;
  }

  // rotate the prefetch pipeline
  tcur[0] = tn0; tcur[1] = tn1;
  xv_use = xv_inf;
  xv_inf = xv_new;

  // (4) raw barrier: only the ds ops must drain (no vmem dependency at the barrier)
  asm volatile("s_waitcnt lgkmcnt(0)" ::: "memory");
  __builtin_amdgcn_sched_barrier(0);
  __builtin_amdgcn_s_barrier();
  __builtin_amdgcn_sched_barrier(0);
}

// ---------------- Kernel 2: recurrence + fused FC head (512 threads, 8 waves) ----------------
__global__ __launch_bounds__(512, 2)
void rnn_fused(const int* __restrict__ x_in, const int* __restrict__ x_len,
               const float* __restrict__ W_hh, const float* __restrict__ T,
               const float* __restrict__ fc1_w, const float* __restrict__ fc1_b,
               const float* __restrict__ fc2_w, const float* __restrict__ fc2_b,
               float* __restrict__ out) {
  __shared__ __align__(16) char smem[40960];

  const int tid  = threadIdx.x;
  const int lane = tid & 63;
  const int wave = tid >> 6;         // 0..7
  const int l15  = lane & 15;
  const int g    = lane >> 4;        // 0..3
  const int j0   = wave * 32;        // 32 j-columns per wave
  const int grow = blockIdx.x * 16;
  const int r    = l15;              // this lane's batch row
  const int swz  = (r & 7) << 4;
  const int rowb = r * 512;

  // W_hh fragments resident in registers (2 mt x 8 kt)
  short8 wfrag[2][8];
  load_wfrags2(W_hh, j0, l15, g, wfrag);

  const int mylen = x_len[grow + r];
  int maxlen = 1;
#pragma unroll
  for (int i = 0; i < 16; ++i) maxlen = max(maxlen, x_len[grow + i]);

  // zero h buffer 0
  {
    int2v* hz = (int2v*)smem;
    const int2v z2 = {0, 0};
    for (int i = tid; i < 1024; i += 512) hz[i] = z2;
  }

  // precomputed LDS byte offsets
  int roff[8], woff[2];
#pragma unroll
  for (int kt = 0; kt < 8; ++kt) roff[kt] = rowb + ((kt * 64 + g * 16) ^ swz);
#pragma unroll
  for (int mt = 0; mt < 2; ++mt) woff[mt] = rowb + (((j0 + mt * 16 + g * 4) * 2) ^ swz);

  // token + T register pipeline prologue
  const int* xrow = x_in + (grow + r) * Ss;
  f32x4 tcur[2];
  {
    const int xv0 = xrow[0];
    const float* tp = T + xv0 * Hh + j0 + g * 4;
    tcur[0] = *(const f32x4*)(tp);
    tcur[1] = *(const f32x4*)(tp + 16);
  }
  int xv_use = xrow[min(1, Ss - 1)];   // x[1]
  int xv_inf = xrow[min(2, Ss - 1)];   // x[2]

  __syncthreads();

  const int mx2 = (maxlen + 1) & ~1;  // even #steps; extra step writes an unread buffer
  for (int t = 0; t < mx2; t += 2) {
    step_phase<0>(smem, wfrag, roff, woff, T, xrow, t,     mylen, j0, g, tcur, xv_use, xv_inf);
    step_phase<1>(smem, wfrag, roff, woff, T, xrow, t + 1, mylen, j0, g, tcur, xv_use, xv_inf);
  }

  // ---------------- fused FC head ----------------
  short8 ffrag[2][8];
  load_wfrags2(fc1_w, j0, l15, g, ffrag);
  f32x4 fb[2];
#pragma unroll
  for (int mt = 0; mt < 2; ++mt)
    fb[mt] = *(const f32x4*)(fc1_b + j0 + mt * 16 + g * 4);

  short8 yf[8];
#pragma unroll
  for (int kt = 0; kt < 8; ++kt) yf[kt] = *(const short8*)(smem + YOFF + roff[kt]);

  const f32x4 Z4 = {0.f, 0.f, 0.f, 0.f};
  f32x4 acc[2], acc2[2];
#pragma unroll
  for (int mt = 0; mt < 2; ++mt) { acc[mt] = fb[mt]; acc2[mt] = Z4; }
#pragma unroll
  for (int kt = 0; kt < 4; ++kt)
#pragma unroll
    for (int mt = 0; mt < 2; ++mt)
      acc[mt] = mfma16(ffrag[mt][kt], yf[kt], acc[mt]);
#pragma unroll
  for (int kt = 4; kt < 8; ++kt)
#pragma unroll
    for (int mt = 0; mt < 2; ++mt)
      acc2[mt] = mfma16(ffrag[mt][kt], yf[kt], acc2[mt]);

  float* z_ld = (float*)(smem + ZOFF);
#pragma unroll
  for (int mt = 0; mt < 2; ++mt) {
    f32x4 z;
    z.x = fmaxf(acc[mt].x + acc2[mt].x, 0.f);
    z.y = fmaxf(acc[mt].y + acc2[mt].y, 0.f);
    z.z = fmaxf(acc[mt].z + acc2[mt].z, 0.f);
    z.w = fmaxf(acc[mt].w + acc2[mt].w, 0.f);
    *(f32x4*)(z_ld + r * 256 + j0 + mt * 16 + g * 4) = z;
  }
  __syncthreads();

  // fc2: 16 rows x 18 classes
  for (int idx = tid; idx < 16 * Cc; idx += 512) {
    const int rr = idx / Cc, c = idx % Cc;
    float s = fc2_b[c];
    const float* wr2 = fc2_w + c * Hh;
    const float* zr  = z_ld + rr * 256;
#pragma unroll 4
    for (int k = 0; k < Hh; k += 4) {
      f32x4 w = *(const f32x4*)(wr2 + k);
      f32x4 z = *(const f32x4*)(zr + k);
      s += w.x * z.x + w.y * z.y + w.z * z.z + w.w * z.w;
    }
    out[(grow + rr) * Cc + c] = s;
  }
}

extern "C" void kernel_launch(void* const* d_in, const int* in_sizes, int n_in,
                              void* d_out, int out_size, void* d_ws, size_t ws_size,
                              hipStream_t stream) {
  const int*   x_in  = (const int*)d_in[0];
  const int*   x_len = (const int*)d_in[1];
  const float* emb   = (const float*)d_in[2];
  const float* W_ih  = (const float*)d_in[3];
  const float* W_hh  = (const float*)d_in[4];
  const float* b_ih  = (const float*)d_in[5];
  const float* b_hh  = (const float*)d_in[6];
  const float* fc1_w = (const float*)d_in[7];
  const float* fc1_b = (const float*)d_in[8];
  const float* fc2_w = (const float*)d_in[9];
  const float* fc2_b = (const float*)d_in[10];
  float* out = (float*)d_out;

  float* T = (float*)d_ws;  // 128*256 f32 = 128 KB

  prep_T<<<Vv, Hh, 0, stream>>>(emb, W_ih, b_ih, b_hh, T);
  rnn_fused<<<Bb / 16, 512, 0, stream>>>(x_in, x_len, W_hh, T,
                                         fc1_w, fc1_b, fc2_w, fc2_b, out);
}

// Round 9
// 404.965 us; speedup vs baseline: 7.1934x; 1.0691x over previous
//
#include <hip/hip_runtime.h>

#define Bb 1024
#define Ss 512
#define Ee 128
#define Hh 256
#define Vv 128
#define Cc 18

// LDS map (12288 B). h layout: byte(row, j) = row*512 + ((j*2) ^ ((row&3)<<6)), rows 0..3.
#define HB1  2048   // h double buffer: [0,2048) + [2048,4096), 4 rows x 512 B
#define YOFF 4096   // y bf16 capture: 4 rows x 512 B, same layout
#define ZOFF 8192   // z f32 [4][256] for the FC head

typedef __attribute__((ext_vector_type(8))) short short8;
typedef __attribute__((ext_vector_type(4))) float f32x4;
typedef __attribute__((ext_vector_type(2))) int int2v;

__device__ __forceinline__ unsigned short f2bf(float f) {
  union { float f; unsigned u; } v; v.f = f;
  return (unsigned short)((v.u + 0x7FFFu + ((v.u >> 16) & 1u)) >> 16);
}

__device__ __forceinline__ f32x4 mfma16(short8 a, short8 b, f32x4 c) {
  return __builtin_amdgcn_mfma_f32_16x16x32_bf16(a, b, c, 0, 0, 0);
}

// tanh = 1 - 2/(e^{2x}+1); correct limits at +-inf, no clamp needed.
__device__ __forceinline__ float ftanh(float x) {
  float e2 = __expf(2.0f * x);
  return 1.0f - 2.0f * __builtin_amdgcn_rcpf(e2 + 1.0f);
}

__device__ __forceinline__ unsigned cvtpk(float a, float b) {
  unsigned r;
  asm("v_cvt_pk_bf16_f32 %0, %1, %2" : "=v"(r) : "v"(a), "v"(b));
  return r;  // lo16 = bf16(a), hi16 = bf16(b)
}

// Load a 32-col slice (2 mt tiles) of a [256][256] f32 row-major matrix as bf16 A-fragments.
__device__ __forceinline__ void load_wfrags2(const float* __restrict__ W, int j0, int l15, int g,
                                             short8 wfrag[2][8]) {
#pragma unroll
  for (int mt = 0; mt < 2; ++mt) {
    const float* wrow = W + (j0 + mt * 16 + l15) * Hh;
#pragma unroll
    for (int kt = 0; kt < 8; ++kt) {
      const float* wp = wrow + kt * 32 + g * 8;
      f32x4 a = *(const f32x4*)(wp);
      f32x4 b = *(const f32x4*)(wp + 4);
      short8 f;
      f[0] = (short)f2bf(a.x); f[1] = (short)f2bf(a.y);
      f[2] = (short)f2bf(a.z); f[3] = (short)f2bf(a.w);
      f[4] = (short)f2bf(b.x); f[5] = (short)f2bf(b.y);
      f[6] = (short)f2bf(b.z); f[7] = (short)f2bf(b.w);
      wfrag[mt][kt] = f;
    }
  }
}

// ---------------- Kernel 1: T[v][j] = emb[v].W_ih[j] + b_ih[j] + b_hh[j] (f32) ----------------
__global__ void prep_T(const float* __restrict__ emb, const float* __restrict__ W_ih,
                       const float* __restrict__ b_ih, const float* __restrict__ b_hh,
                       float* __restrict__ T) {
  __shared__ float elds[Ee];
  const int v = blockIdx.x, j = threadIdx.x;
  if (j < Ee) elds[j] = emb[v * Ee + j];
  __syncthreads();
  float s = b_ih[j] + b_hh[j];
  const float* wr = W_ih + j * Ee;
#pragma unroll 8
  for (int e = 0; e < Ee; e += 4) {
    f32x4 w = *(const f32x4*)(wr + e);
    f32x4 x = *(const f32x4*)(elds + e);
    s += w.x * x.x + w.y * x.y + w.z * x.z + w.w * x.w;
  }
  T[v * Hh + j] = s;
}

// ---------------- one RNN step (8 waves x 32 j-cols; 4 batch rows, B-cols 4-15 duplicated) ----
// Pipeline invariants: tcur = T rows for x[t]; xv_use = x[t+1]; xv_inf = x[t+2];
// the token load issued this step is x[t+3].
template <int PAR>
__device__ __forceinline__ void step_phase(char* smem, const short8 (&wf)[2][8],
                                           const int (&roff)[8], const int (&woff)[2],
                                           const float* __restrict__ T,
                                           const int* __restrict__ xrow,
                                           int t, int mylen, int j0, int g, bool vr,
                                           f32x4 (&tcur)[2], int& xv_use, int& xv_inf) {
  char* RB = smem + (PAR ? HB1 : 0);
  char* WB = smem + (PAR ? 0 : HB1);

  // (1) next step's T gather (f32 -> registers) + token for t+3
  const float* tp = T + xv_use * Hh + j0 + g * 4;
  f32x4 tn0 = *(const f32x4*)(tp);
  f32x4 tn1 = *(const f32x4*)(tp + 16);
  const int xv_new = xrow[min(t + 3, Ss - 1)];

  // (2) h-reads pipelined into the MFMA stream.
  //     Lanes r>=4 read the SAME addresses as r&3 -> LDS broadcast (256 distinct B/read).
  short8 hf[8];
  hf[0] = *(const short8*)(RB + roff[0]);
  hf[1] = *(const short8*)(RB + roff[1]);

  f32x4 aA[2], aB[2];
  const f32x4 Z4 = {0.f, 0.f, 0.f, 0.f};
  aA[0] = tcur[0]; aA[1] = tcur[1]; aB[0] = Z4; aB[1] = Z4;

#pragma unroll
  for (int kt = 0; kt < 8; ++kt) {
    if (kt < 6) hf[kt + 2] = *(const short8*)(RB + roff[kt + 2]);
    if ((kt & 1) == 0) {
      aA[0] = mfma16(wf[0][kt], hf[kt], aA[0]);
      aA[1] = mfma16(wf[1][kt], hf[kt], aA[1]);
    } else {
      aB[0] = mfma16(wf[0][kt], hf[kt], aB[0]);
      aB[1] = mfma16(wf[1][kt], hf[kt], aB[1]);
    }
  }

  // (3) epilogue: combine, tanh, pack; only valid-row lanes (r<4) write
  const bool emit = (t == mylen - 1);
#pragma unroll
  for (int mt = 0; mt < 2; ++mt) {
    float s0 = aA[mt].x + aB[mt].x;
    float s1 = aA[mt].y + aB[mt].y;
    float s2 = aA[mt].z + aB[mt].z;
    float s3 = aA[mt].w + aB[mt].w;
    int2v pk;
    pk.x = (int)cvtpk(ftanh(s0), ftanh(s1));
    pk.y = (int)cvtpk(ftanh(s2), ftanh(s3));
    if (vr) {
      *(int2v*)(WB + woff[mt]) = pk;
      if (emit) *(int2v*)(smem + YOFF + woff[mt]) = pk;
    }
  }

  // rotate the prefetch pipeline
  tcur[0] = tn0; tcur[1] = tn1;
  xv_use = xv_inf;
  xv_inf = xv_new;

  // (4) raw barrier: only ds ops must drain
  asm volatile("s_waitcnt lgkmcnt(0)" ::: "memory");
  __builtin_amdgcn_sched_barrier(0);
  __builtin_amdgcn_s_barrier();
  __builtin_amdgcn_sched_barrier(0);
}

// ---------------- Kernel 2: recurrence + fused FC head (256 blocks x 4 rows, 512 threads) ----
__global__ __launch_bounds__(512, 2)
void rnn_fused(const int* __restrict__ x_in, const int* __restrict__ x_len,
               const float* __restrict__ W_hh, const float* __restrict__ T,
               const float* __restrict__ fc1_w, const float* __restrict__ fc1_b,
               const float* __restrict__ fc2_w, const float* __restrict__ fc2_b,
               float* __restrict__ out) {
  __shared__ __align__(16) char smem[12288];

  const int tid  = threadIdx.x;
  const int lane = tid & 63;
  const int wave = tid >> 6;         // 0..7
  const int l15  = lane & 15;
  const int g    = lane >> 4;        // 0..3
  const int j0   = wave * 32;        // 32 j-columns per wave
  const int grow = blockIdx.x * 4;   // 4 batch rows per block
  const int r    = l15;
  const int rr   = r & 3;            // duplicated row index
  const bool vr  = (r < 4);          // valid-row lane

  // W_hh fragments resident in registers (2 mt x 8 kt)
  short8 wfrag[2][8];
  load_wfrags2(W_hh, j0, l15, g, wfrag);

  const int mylen = x_len[grow + rr];
  int maxlen = 1;
#pragma unroll
  for (int i = 0; i < 4; ++i) maxlen = max(maxlen, x_len[grow + i]);

  // zero h buffer 0 (2048 B)
  ((int*)smem)[tid < 512 ? tid : 0] = 0;

  // LDS byte offsets. Layout: byte(row,j) = row*512 + ((j*2) ^ ((row&3)<<6))
  int roff[8], woff[2];
#pragma unroll
  for (int kt = 0; kt < 8; ++kt) roff[kt] = rr * 512 + ((kt * 64 + g * 16) ^ (rr << 6));
#pragma unroll
  for (int mt = 0; mt < 2; ++mt)
    woff[mt] = rr * 512 + (((j0 + mt * 16 + g * 4) * 2) ^ (rr << 6));

  // token + T register pipeline prologue
  const int* xrow = x_in + (grow + rr) * Ss;
  f32x4 tcur[2];
  {
    const int xv0 = xrow[0];
    const float* tp = T + xv0 * Hh + j0 + g * 4;
    tcur[0] = *(const f32x4*)(tp);
    tcur[1] = *(const f32x4*)(tp + 16);
  }
  int xv_use = xrow[min(1, Ss - 1)];   // x[1]
  int xv_inf = xrow[min(2, Ss - 1)];   // x[2]

  __syncthreads();

  const int mx2 = (maxlen + 1) & ~1;  // even #steps; extra step writes an unread buffer
  for (int t = 0; t < mx2; t += 2) {
    step_phase<0>(smem, wfrag, roff, woff, T, xrow, t,     mylen, j0, g, vr, tcur, xv_use, xv_inf);
    step_phase<1>(smem, wfrag, roff, woff, T, xrow, t + 1, mylen, j0, g, vr, tcur, xv_use, xv_inf);
  }

  // ---------------- fused FC head ----------------
  short8 ffrag[2][8];
  load_wfrags2(fc1_w, j0, l15, g, ffrag);
  f32x4 fb[2];
#pragma unroll
  for (int mt = 0; mt < 2; ++mt)
    fb[mt] = *(const f32x4*)(fc1_b + j0 + mt * 16 + g * 4);

  short8 yf[8];
#pragma unroll
  for (int kt = 0; kt < 8; ++kt) yf[kt] = *(const short8*)(smem + YOFF + roff[kt]);

  const f32x4 Z4 = {0.f, 0.f, 0.f, 0.f};
  f32x4 acc[2], acc2[2];
#pragma unroll
  for (int mt = 0; mt < 2; ++mt) { acc[mt] = fb[mt]; acc2[mt] = Z4; }
#pragma unroll
  for (int kt = 0; kt < 4; ++kt)
#pragma unroll
    for (int mt = 0; mt < 2; ++mt)
      acc[mt] = mfma16(ffrag[mt][kt], yf[kt], acc[mt]);
#pragma unroll
  for (int kt = 4; kt < 8; ++kt)
#pragma unroll
    for (int mt = 0; mt < 2; ++mt)
      acc2[mt] = mfma16(ffrag[mt][kt], yf[kt], acc2[mt]);

  float* z_ld = (float*)(smem + ZOFF);  // [4][256] f32
#pragma unroll
  for (int mt = 0; mt < 2; ++mt) {
    f32x4 z;
    z.x = fmaxf(acc[mt].x + acc2[mt].x, 0.f);
    z.y = fmaxf(acc[mt].y + acc2[mt].y, 0.f);
    z.z = fmaxf(acc[mt].z + acc2[mt].z, 0.f);
    z.w = fmaxf(acc[mt].w + acc2[mt].w, 0.f);
    if (vr) *(f32x4*)(z_ld + rr * 256 + j0 + mt * 16 + g * 4) = z;
  }
  __syncthreads();

  // fc2: 4 rows x 18 classes
  for (int idx = tid; idx < 4 * Cc; idx += 512) {
    const int r2 = idx / Cc, c = idx % Cc;
    float s = fc2_b[c];
    const float* wr2 = fc2_w + c * Hh;
    const float* zr  = z_ld + r2 * 256;
#pragma unroll 4
    for (int k = 0; k < Hh; k += 4) {
      f32x4 w = *(const f32x4*)(wr2 + k);
      f32x4 z = *(const f32x4*)(zr + k);
      s += w.x * z.x + w.y * z.y + w.z * z.z + w.w * z.w;
    }
    out[(grow + r2) * Cc + c] = s;
  }
}

extern "C" void kernel_launch(void* const* d_in, const int* in_sizes, int n_in,
                              void* d_out, int out_size, void* d_ws, size_t ws_size,
                              hipStream_t stream) {
  const int*   x_in  = (const int*)d_in[0];
  const int*   x_len = (const int*)d_in[1];
  const float* emb   = (const float*)d_in[2];
  const float* W_ih  = (const float*)d_in[3];
  const float* W_hh  = (const float*)d_in[4];
  const float* b_ih  = (const float*)d_in[5];
  const float* b_hh  = (const float*)d_in[6];
  const float* fc1_w = (const float*)d_in[7];
  const float* fc1_b = (const float*)d_in[8];
  const float* fc2_w = (const float*)d_in[9];
  const float* fc2_b = (const float*)d_in[10];
  float* out = (float*)d_out;

  float* T = (float*)d_ws;  // 128*256 f32 = 128 KB

  prep_T<<<Vv, Hh, 0, stream>>>(emb, W_ih, b_ih, b_hh, T);
  rnn_fused<<<Bb / 4, 512, 0, stream>>>(x_in, x_len, W_hh, T,
                                        fc1_w, fc1_b, fc2_w, fc2_b, out);
}

// Round 10
// 379.443 us; speedup vs baseline: 7.6773x; 1.0673x over previous
//
#include <hip/hip_runtime.h>

#define Bb 1024
#define Ss 512
#define Ee 128
#define Hh 256
#define Vv 128
#define Cc 18

// LDS map (10240 B). h layout: byte(row, bytecol) = row*512 + (bytecol ^ (row<<6)), rows 0..3.
#define HB1  2048   // h double buffer: [0,2048) + [2048,4096)
#define YOFF 4096   // y bf16 capture: 4 rows x 512 B, same layout
#define ZOFF 6144   // z f32 [4][256] for the FC head

typedef __attribute__((ext_vector_type(8))) short short8;
typedef __attribute__((ext_vector_type(4))) float f32x4;
typedef __attribute__((ext_vector_type(2))) int int2v;

__device__ __forceinline__ unsigned short f2bf(float f) {
  union { float f; unsigned u; } v; v.f = f;
  return (unsigned short)((v.u + 0x7FFFu + ((v.u >> 16) & 1u)) >> 16);
}

__device__ __forceinline__ f32x4 mfma16(short8 a, short8 b, f32x4 c) {
  return __builtin_amdgcn_mfma_f32_16x16x32_bf16(a, b, c, 0, 0, 0);
}

// tanh = 1 - 2/(e^{2x}+1); correct limits at +-inf, no clamp needed.
__device__ __forceinline__ float ftanh(float x) {
  float e2 = __expf(2.0f * x);
  return 1.0f - 2.0f * __builtin_amdgcn_rcpf(e2 + 1.0f);
}

__device__ __forceinline__ unsigned cvtpk(float a, float b) {
  unsigned r;
  asm("v_cvt_pk_bf16_f32 %0, %1, %2" : "=v"(r) : "v"(a), "v"(b));
  return r;  // lo16 = bf16(a), hi16 = bf16(b)
}

// Load a 16-col slice (rows j0..j0+15) of a [256][256] f32 row-major matrix as bf16 A-fragments.
__device__ __forceinline__ void load_wfrags1(const float* __restrict__ W, int j0, int l15, int g,
                                             short8 (&wfrag)[8]) {
  const float* wrow = W + (j0 + l15) * Hh;
#pragma unroll
  for (int kt = 0; kt < 8; ++kt) {
    const float* wp = wrow + kt * 32 + g * 8;
    f32x4 a = *(const f32x4*)(wp);
    f32x4 b = *(const f32x4*)(wp + 4);
    short8 f;
    f[0] = (short)f2bf(a.x); f[1] = (short)f2bf(a.y);
    f[2] = (short)f2bf(a.z); f[3] = (short)f2bf(a.w);
    f[4] = (short)f2bf(b.x); f[5] = (short)f2bf(b.y);
    f[6] = (short)f2bf(b.z); f[7] = (short)f2bf(b.w);
    wfrag[kt] = f;
  }
}

// ---------------- Kernel 1: T[v][j] = emb[v].W_ih[j] + b_ih[j] + b_hh[j] (f32) ----------------
__global__ void prep_T(const float* __restrict__ emb, const float* __restrict__ W_ih,
                       const float* __restrict__ b_ih, const float* __restrict__ b_hh,
                       float* __restrict__ T) {
  __shared__ float elds[Ee];
  const int v = blockIdx.x, j = threadIdx.x;
  if (j < Ee) elds[j] = emb[v * Ee + j];
  __syncthreads();
  float s = b_ih[j] + b_hh[j];
  const float* wr = W_ih + j * Ee;
#pragma unroll 8
  for (int e = 0; e < Ee; e += 4) {
    f32x4 w = *(const f32x4*)(wr + e);
    f32x4 x = *(const f32x4*)(elds + e);
    s += w.x * x.x + w.y * x.y + w.z * x.z + w.w * x.w;
  }
  T[v * Hh + j] = s;
}

// ---------------- one RNN step (16 waves x 16 j-cols; 4 batch rows, B-cols 4-15 dup) --------
// Pipeline invariants: t_use = T row for x[t] (consumed); xv_use = x[t+1] (drives this step's
// T prefetch into t_load); xv_inf = x[t+2]; token load issued this step = x[t+3].
template <int PAR>
__device__ __forceinline__ void step_phase(char* smem, const short8 (&wf)[8],
                                           const int (&roff)[8], int woff,
                                           const float* __restrict__ T,
                                           const int* __restrict__ xrow,
                                           int t, int mylen, int j0, int g, bool vr,
                                           f32x4& t_use, f32x4& t_load,
                                           int& xv_use, int& xv_inf) {
  char* RB = smem + (PAR ? HB1 : 0);
  char* WB = smem + (PAR ? 0 : HB1);

  // (1) next step's T slice (f32 -> the alternate register) + token for t+3
  t_load = *(const f32x4*)(T + xv_use * Hh + j0 + g * 4);
  const int xv_new = xrow[min(t + 3, Ss - 1)];

  // (2) h-reads pipelined into the MFMA stream; lanes with r>=4 broadcast-read r&3's data.
  short8 hf[8];
  hf[0] = *(const short8*)(RB + roff[0]);
  hf[1] = *(const short8*)(RB + roff[1]);

  const f32x4 Z4 = {0.f, 0.f, 0.f, 0.f};
  f32x4 aA, aB;
#pragma unroll
  for (int kt = 0; kt < 8; ++kt) {
    if (kt < 6) hf[kt + 2] = *(const short8*)(RB + roff[kt + 2]);
    if (kt == 0)            aA = mfma16(wf[0], hf[0], t_use);  // chain A seeded with T
    else if (kt == 1)       aB = mfma16(wf[1], hf[1], Z4);     // chain B seeded with 0
    else if ((kt & 1) == 0) aA = mfma16(wf[kt], hf[kt], aA);
    else                    aB = mfma16(wf[kt], hf[kt], aB);
  }

  // (3) epilogue: combine, tanh, pack; only valid-row lanes write
  const bool emit = (t == mylen - 1);
  float s0 = aA.x + aB.x;
  float s1 = aA.y + aB.y;
  float s2 = aA.z + aB.z;
  float s3 = aA.w + aB.w;
  int2v pk;
  pk.x = (int)cvtpk(ftanh(s0), ftanh(s1));
  pk.y = (int)cvtpk(ftanh(s2), ftanh(s3));
  if (vr) {
    *(int2v*)(WB + woff) = pk;
    if (emit) *(int2v*)(smem + YOFF + woff) = pk;
  }

  // rotate token pipeline (T rotate is free: registers alternate via t_use/t_load refs)
  xv_use = xv_inf;
  xv_inf = xv_new;

  // (4) raw barrier: only ds ops must drain; no trailing sched_barrier (let next phase hoist VALU)
  asm volatile("s_waitcnt lgkmcnt(0)" ::: "memory");
  __builtin_amdgcn_sched_barrier(0);
  __builtin_amdgcn_s_barrier();
}

// ---------------- Kernel 2: recurrence + fused FC head (256 blocks x 4 rows, 1024 thr) ------
__global__ __launch_bounds__(1024, 4)
void rnn_fused(const int* __restrict__ x_in, const int* __restrict__ x_len,
               const float* __restrict__ W_hh, const float* __restrict__ T,
               const float* __restrict__ fc1_w, const float* __restrict__ fc1_b,
               const float* __restrict__ fc2_w, const float* __restrict__ fc2_b,
               float* __restrict__ out) {
  __shared__ __align__(16) char smem[10240];

  const int tid  = threadIdx.x;
  const int lane = tid & 63;
  const int wave = tid >> 6;         // 0..15
  const int l15  = lane & 15;
  const int g    = lane >> 4;        // 0..3
  const int j0   = wave * 16;        // 16 j-columns per wave
  const int grow = blockIdx.x * 4;   // 4 batch rows per block
  const int rr   = l15 & 3;          // duplicated row index
  const bool vr  = (l15 < 4);        // valid-row lane

  // W_hh fragments resident in registers (8 kt)
  short8 wfrag[8];
  load_wfrags1(W_hh, j0, l15, g, wfrag);

  const int mylen = x_len[grow + rr];
  int maxlen = 1;
#pragma unroll
  for (int i = 0; i < 4; ++i) maxlen = max(maxlen, x_len[grow + i]);

  // zero h buffer 0 (2048 B)
  if (tid < 512) ((int*)smem)[tid] = 0;

  // LDS byte offsets. Layout: byte(row,bc) = row*512 + (bc ^ (row<<6))
  int roff[8];
#pragma unroll
  for (int kt = 0; kt < 8; ++kt) roff[kt] = rr * 512 + ((kt * 64 + g * 16) ^ (rr << 6));
  const int woff = rr * 512 + (((j0 + g * 4) * 2) ^ (rr << 6));

  // token + T register pipeline prologue
  const int* xrow = x_in + (grow + rr) * Ss;
  f32x4 tA, tB;
  tA = *(const f32x4*)(T + xrow[0] * Hh + j0 + g * 4);  // T for step 0
  int xv_use = xrow[min(1, Ss - 1)];   // x[1]
  int xv_inf = xrow[min(2, Ss - 1)];   // x[2]

  __syncthreads();

  const int mx2 = (maxlen + 1) & ~1;  // even #steps; extra step writes an unread buffer
  for (int t = 0; t < mx2; t += 2) {
    step_phase<0>(smem, wfrag, roff, woff, T, xrow, t,     mylen, j0, g, vr, tA, tB, xv_use, xv_inf);
    step_phase<1>(smem, wfrag, roff, woff, T, xrow, t + 1, mylen, j0, g, vr, tB, tA, xv_use, xv_inf);
  }

  // ---------------- fused FC head ----------------
  short8 ffrag[8];
  load_wfrags1(fc1_w, j0, l15, g, ffrag);
  const f32x4 fb = *(const f32x4*)(fc1_b + j0 + g * 4);

  short8 yf[8];
#pragma unroll
  for (int kt = 0; kt < 8; ++kt) yf[kt] = *(const short8*)(smem + YOFF + roff[kt]);

  const f32x4 Z4 = {0.f, 0.f, 0.f, 0.f};
  f32x4 aA, aB;
#pragma unroll
  for (int kt = 0; kt < 8; ++kt) {
    if (kt == 0)            aA = mfma16(ffrag[0], yf[0], fb);
    else if (kt == 1)       aB = mfma16(ffrag[1], yf[1], Z4);
    else if ((kt & 1) == 0) aA = mfma16(ffrag[kt], yf[kt], aA);
    else                    aB = mfma16(ffrag[kt], yf[kt], aB);
  }

  float* z_ld = (float*)(smem + ZOFF);  // [4][256] f32
  {
    f32x4 z;
    z.x = fmaxf(aA.x + aB.x, 0.f);
    z.y = fmaxf(aA.y + aB.y, 0.f);
    z.z = fmaxf(aA.z + aB.z, 0.f);
    z.w = fmaxf(aA.w + aB.w, 0.f);
    if (vr) *(f32x4*)(z_ld + rr * 256 + j0 + g * 4) = z;
  }
  __syncthreads();

  // fc2: 4 rows x 18 classes
  if (tid < 4 * Cc) {
    const int r2 = tid / Cc, c = tid % Cc;
    float s = fc2_b[c];
    const float* wr2 = fc2_w + c * Hh;
    const float* zr  = z_ld + r2 * 256;
#pragma unroll 4
    for (int k = 0; k < Hh; k += 4) {
      f32x4 w = *(const f32x4*)(wr2 + k);
      f32x4 z = *(const f32x4*)(zr + k);
      s += w.x * z.x + w.y * z.y + w.z * z.z + w.w * z.w;
    }
    out[(grow + r2) * Cc + c] = s;
  }
}

extern "C" void kernel_launch(void* const* d_in, const int* in_sizes, int n_in,
                              void* d_out, int out_size, void* d_ws, size_t ws_size,
                              hipStream_t stream) {
  const int*   x_in  = (const int*)d_in[0];
  const int*   x_len = (const int*)d_in[1];
  const float* emb   = (const float*)d_in[2];
  const float* W_ih  = (const float*)d_in[3];
  const float* W_hh  = (const float*)d_in[4];
  const float* b_ih  = (const float*)d_in[5];
  const float* b_hh  = (const float*)d_in[6];
  const float* fc1_w = (const float*)d_in[7];
  const float* fc1_b = (const float*)d_in[8];
  const float* fc2_w = (const float*)d_in[9];
  const float* fc2_b = (const float*)d_in[10];
  float* out = (float*)d_out;

  float* T = (float*)d_ws;  // 128*256 f32 = 128 KB

  prep_T<<<Vv, Hh, 0, stream>>>(emb, W_ih, b_ih, b_hh, T);
  rnn_fused<<<Bb / 4, 1024, 0, stream>>>(x_in, x_len, W_hh, T,
                                         fc1_w, fc1_b, fc2_w, fc2_b, out);
}